// Round 12
// baseline (493.237 us; speedup 1.0000x reference)
//
#include <hip/hip_runtime.h>

// Problem: bs=8, seq=16, hw=32*32=1024, ck=256, cv=3, steps=seq-1=15
// R17 = R16 resubmit (R16 hit an infra container failure; no mechanism in the
// kernel can hang: no coop launch, no spins, regs ~200 < 256 cap).
// Pre-commitment: if this fails twice again, revert to R15 + scan-only fix.
// Design: R15 (verified 467.6us, fragment-major A-layout) + two latency fixes:
//  - scan_state (84us @ 30% HBM, latency-bound): att gate loads hoisted out
//    of the EMA loop (were a serial per-iter dependency), k prefetch depth 2.
//  - attn_step (~25.5us/step): both mats' A-fragments (16 loads, 256B/lane)
//    issued before any MFMA -> mat1's L2 stream hides under mat0's
//    MFMA+absorb. +32 VGPR on a 128-VGPR body with cap 256 (512,1).
#define BS 8
#define SEQ 16
#define HW 1024
#define CK 256
#define CV 3
#define STEPS 15

#define SKP 264           // padded fp16 LDS row stride (256+8)
#define KSTR (HW * CK)    // u16 elements per (b,step) image = 262144

typedef unsigned short u16;
typedef _Float16 half8 __attribute__((ext_vector_type(8)));  // MFMA A/B frag
typedef float floatx4 __attribute__((ext_vector_type(4)));   // MFMA C/D frag

__device__ __forceinline__ u16 f2h(float f) {
  _Float16 h = (_Float16)f;
  return __builtin_bit_cast(unsigned short, h);
}
__device__ __forceinline__ float h2f(u16 u) {
  _Float16 h = __builtin_bit_cast(_Float16, u);
  return (float)h;
}

// ---- scan_state (once, fully parallel): kh_all = fp16(k[:, i]) for all i,
//      m_kh_all[i] = m_k EMA (fp16 state, fp32 math) -- both FRAGMENT-MAJOR;
//      pv0 = v[:,0], m_v0 = 0, gt = v[:,1:].
//      Thread = (b, pb, kk, g): one 8-elem granule chain; writes coalesce to
//      1KB/wave-inst. att gates preloaded (15 upfront); k prefetch depth 2. ----
__global__ __launch_bounds__(256) void scan_state(
    const float* __restrict__ k, const float* __restrict__ v,
    const float* __restrict__ att,
    u16* __restrict__ kh_all, u16* __restrict__ m_kh_all,
    float* __restrict__ pv0, float* __restrict__ mv0,
    float* __restrict__ out)
{
  long idx = (long)blockIdx.x * 256 + threadIdx.x;
  long stride = (long)gridDim.x * 256;
  const long NT = (long)BS * 64 * 8 * 64;      // 262,144 granule chains
  for (long t = idx; t < NT; t += stride) {
    long b = t >> 15;                          // / (64*8*64)
    long rr = t & 32767;
    long pb = rr >> 9;                         // p-block (64 per image)
    long kk = (rr >> 6) & 7;                   // k-column block
    long g  = rr & 63;                         // granule = lane = rg*16+r
    long p   = pb * 16 + (g & 15);             // row
    long col = kk * 32 + (g >> 4) * 8;         // first of 8 cols
    long toff = (pb * 8 + kk) * 512 + g * 8;   // u16 offset within image
    const float* kp = k + ((long)b * SEQ * HW + p) * CK + col;
    const float* ap = att + (long)b * SEQ * HW + p;
    // hoist all att gate loads (were a serial per-iteration dependency)
    float av[STEPS];
    #pragma unroll
    for (int i = 0; i < STEPS; ++i) av[i] = ap[(long)i * HW];
    u16 mh[8] = {0, 0, 0, 0, 0, 0, 0, 0};
    // k prefetch depth 2
    float4 l0 = *(const float4*)kp;
    float4 h0 = *(const float4*)(kp + 4);
    float4 l1 = *(const float4*)(kp + KSTR);
    float4 h1 = *(const float4*)(kp + KSTR + 4);
    for (int i = 0; i < SEQ; ++i) {
      float4 lo = l0, hi = h0;
      l0 = l1; h0 = h1;
      if (i + 2 < SEQ) {
        l1 = *(const float4*)(kp + (long)(i + 2) * KSTR);
        h1 = *(const float4*)(kp + (long)(i + 2) * KSTR + 4);
      }
      float kf[8] = {lo.x, lo.y, lo.z, lo.w, hi.x, hi.y, hi.z, hi.w};
      u16 h8[8];
      #pragma unroll
      for (int j = 0; j < 8; ++j) h8[j] = f2h(kf[j]);
      *(int4*)(kh_all + (long)(b * SEQ + i) * KSTR + toff) = *(const int4*)h8;
      if (i < STEPS) {
        float gg = 1.0f / (1.0f + __expf(-av[i])), og = 1.0f - gg;
        #pragma unroll
        for (int j = 0; j < 8; ++j)
          mh[j] = f2h(fmaf(gg, kf[j], og * h2f(mh[j])));
        *(int4*)(m_kh_all + (long)(b * STEPS + i) * KSTR + toff) = *(const int4*)mh;
      }
    }
  }
  // pv0 = v[:,0], m_v0 = 0
  const long NV = (long)BS * HW * CV;
  for (long t = idx; t < NV; t += stride) {
    long b = t / (HW * CV), r = t - b * (HW * CV);
    pv0[t] = v[(long)b * SEQ * HW * CV + r];
    mv0[t] = 0.0f;
  }
  // gt = v[:,1:]
  const long NG = (long)BS * STEPS * HW * CV;
  for (long t = idx; t < NG; t += stride) {
    long b = t / (STEPS * HW * CV), r = t - b * (STEPS * HW * CV);
    long i = r / (HW * CV), rr = r - i * (HW * CV);
    out[NG + t] = v[((long)b * SEQ + i + 1) * (HW * CV) + rr];
  }
}

// --------- per-step fused dual-attention: barrier-free wave-autonomous ---------
// grid (BS, 32): block = (batch, 32 q-rows), 512 thr = 8 waves.
// Wave w owns p-range [w*128, (w+1)*128) as 4 chunks of 32.
// MFMA: A = p-rows (fragment-major: 1KB contiguous per wave instruction;
// BOTH mats' fragments issued before any MFMA so mat1's stream hides under
// mat0's MFMA+absorb), B = q-tile (regs). D[p][q]: lane q=lane&15, p-rows =
// (lane>>4)*4+reg -> online softmax over p is in-register.
__global__ __launch_bounds__(512, 1) void attn_step(
    const u16* __restrict__ kh_all, const u16* __restrict__ m_kh_all,
    const float* __restrict__ v, const int* __restrict__ seq_mask,
    const float* __restrict__ att,
    const float* __restrict__ mv_in, float* __restrict__ mv_out,
    const float* __restrict__ pv_in, float* __restrict__ pv_out,
    float* __restrict__ out, int step)
{
  __shared__ u16 Kq[32 * SKP];          // q-tile fp16 (16.9 KB)
  __shared__ float Vp[HW * CV];         // prev_v staged (12 KB)
  __shared__ float Vm[HW * CV];         // m_v (updated) staged (12 KB)
  __shared__ float Mg[8][2][32][5];     // per-wave partial states (10.2 KB)

  const int b = blockIdx.x;
  const int q0 = blockIdx.y * 32;
  const int tid = threadIdx.x;
  const int w = tid >> 6, lane = tid & 63;
  const int r = lane & 15, rg = lane >> 4;

  const u16* Kn = kh_all + (long)(b * SEQ + step + 1) * KSTR;  // q side
  const u16* Kc = kh_all + (long)(b * SEQ + step) * KSTR;      // p side
  const u16* Mb = m_kh_all + (long)(b * STEPS + step) * KSTR;  // p side

  { // stage q-tile: 1024 16B-chunks, LINEAR reads from fragment-major layout
    #pragma unroll
    for (int j = 0; j < 2; ++j) {
      int c = tid + j * 512;
      int pbl = c >> 9, rem = c & 511;
      int kk2 = rem >> 6, g2 = rem & 63;
      int r2 = g2 & 15, rg2 = g2 >> 4;
      *(int4*)&Kq[(pbl * 16 + r2) * SKP + kk2 * 32 + rg2 * 8] =
          *(const int4*)(Kn + (long)(q0 >> 4) * 4096 + (long)c * 8);
    }
  }
  { // stage V values + fused m_v EMA: m_v_i = g*pv_i + (1-g)*m_v_{i-1}
    const float* ar = att + (long)(b * SEQ + step) * HW;
    #pragma unroll
    for (int j = 0; j < 2; ++j) {
      int row = tid + j * 512;
      float a = ar[row];
      float g = 1.0f / (1.0f + __expf(-a));
      float og = 1.0f - g;
      long base = (long)(b * HW + row) * CV;
      #pragma unroll
      for (int c = 0; c < CV; ++c) {
        float pv = pv_in[base + c];
        float mv = fmaf(g, pv, og * mv_in[base + c]);
        Vp[row * CV + c] = pv;
        Vm[row * CV + c] = mv;
        if (blockIdx.y == 0) mv_out[base + c] = mv;
      }
    }
  }
  __syncthreads();

  // B fragments (q-tile) held in registers: 2 q-subtiles x 8 k-steps
  half8 Bq[2][8];
  #pragma unroll
  for (int qi = 0; qi < 2; ++qi)
    #pragma unroll
    for (int kk = 0; kk < 8; ++kk)
      Bq[qi][kk] = *(const half8*)&Kq[(qi * 16 + r) * SKP + kk * 32 + rg * 8];

  // online state per (mat, qi): q-col = qi*16 + r, p-subset = this lane's rows
  float mx[2][2], l[2][2], acc[2][2][3];
  #pragma unroll
  for (int m = 0; m < 2; ++m)
    #pragma unroll
    for (int qi = 0; qi < 2; ++qi) {
      mx[m][qi] = -1e30f; l[m][qi] = 0.f;
      acc[m][qi][0] = acc[m][qi][1] = acc[m][qi][2] = 0.f;
    }

  #pragma unroll
  for (int pc = 0; pc < 4; ++pc) {
    #pragma unroll
    for (int pi = 0; pi < 2; ++pi) {
      const int pr = w * 128 + pc * 32 + pi * 16;
      const int pb = pr >> 4;                  // fragment-major tile row
      // issue BOTH mats' A-fragments before any MFMA (256B/lane in flight)
      const u16* A0b = Kc + (long)pb * 4096 + lane * 8;
      const u16* A1b = Mb + (long)pb * 4096 + lane * 8;
      half8 A0[8], A1[8];
      #pragma unroll
      for (int kk = 0; kk < 8; ++kk) A0[kk] = *(const half8*)(A0b + kk * 512);
      #pragma unroll
      for (int kk = 0; kk < 8; ++kk) A1[kk] = *(const half8*)(A1b + kk * 512);
      // V values for this lane's 4 p-rows, both mats, from LDS
      float Vv0[4][3], Vv1[4][3];
      #pragma unroll
      for (int j = 0; j < 4; ++j) {
        const float* vp0 = Vp + (pr + rg * 4 + j) * CV;
        const float* vp1 = Vm + (pr + rg * 4 + j) * CV;
        Vv0[j][0] = vp0[0]; Vv0[j][1] = vp0[1]; Vv0[j][2] = vp0[2];
        Vv1[j][0] = vp1[0]; Vv1[j][1] = vp1[1]; Vv1[j][2] = vp1[2];
      }
      #pragma unroll
      for (int mat = 0; mat < 2; ++mat) {
        floatx4 c0 = {0.f, 0.f, 0.f, 0.f}, c1 = {0.f, 0.f, 0.f, 0.f};
        #pragma unroll
        for (int kk = 0; kk < 8; ++kk) {
          half8 Af = mat ? A1[kk] : A0[kk];
          c0 = __builtin_amdgcn_mfma_f32_16x16x32_f16(Af, Bq[0][kk], c0, 0, 0, 0);
          c1 = __builtin_amdgcn_mfma_f32_16x16x32_f16(Af, Bq[1][kk], c1, 0, 0, 0);
        }
        // absorb 4 p-values per qi into online state
        #pragma unroll
        for (int qi = 0; qi < 2; ++qi) {
          floatx4 cc = qi ? c1 : c0;
          float tmax = fmaxf(fmaxf(cc[0], cc[1]), fmaxf(cc[2], cc[3]));
          tmax = fmaxf(tmax, mx[mat][qi]);
          float sc = __expf(mx[mat][qi] - tmax);
          l[mat][qi] *= sc;
          acc[mat][qi][0] *= sc; acc[mat][qi][1] *= sc; acc[mat][qi][2] *= sc;
          #pragma unroll
          for (int j = 0; j < 4; ++j) {
            float e = __expf(cc[j] - tmax);
            l[mat][qi] += e;
            float* Vvj = mat ? Vv1[j] : Vv0[j];
            acc[mat][qi][0] = fmaf(e, Vvj[0], acc[mat][qi][0]);
            acc[mat][qi][1] = fmaf(e, Vvj[1], acc[mat][qi][1]);
            acc[mat][qi][2] = fmaf(e, Vvj[2], acc[mat][qi][2]);
          }
          mx[mat][qi] = tmax;
        }
      }
    }
  }

  // merge the 4 rowgroup partials (lanes r, r+16, r+32, r+48) via shuffle
  #pragma unroll
  for (int off = 16; off <= 32; off <<= 1) {
    #pragma unroll
    for (int m = 0; m < 2; ++m)
      #pragma unroll
      for (int qi = 0; qi < 2; ++qi) {
        float m2 = __shfl_xor(mx[m][qi], off);
        float l2 = __shfl_xor(l[m][qi], off);
        float b0s = __shfl_xor(acc[m][qi][0], off);
        float b1s = __shfl_xor(acc[m][qi][1], off);
        float b2s = __shfl_xor(acc[m][qi][2], off);
        float mn = fmaxf(mx[m][qi], m2);
        float e1 = __expf(mx[m][qi] - mn), e2 = __expf(m2 - mn);
        l[m][qi] = l[m][qi] * e1 + l2 * e2;
        acc[m][qi][0] = acc[m][qi][0] * e1 + b0s * e2;
        acc[m][qi][1] = acc[m][qi][1] * e1 + b1s * e2;
        acc[m][qi][2] = acc[m][qi][2] * e1 + b2s * e2;
        mx[m][qi] = mn;
      }
  }
  if (rg == 0) {
    #pragma unroll
    for (int m = 0; m < 2; ++m)
      #pragma unroll
      for (int qi = 0; qi < 2; ++qi) {
        float* d = Mg[w][m][qi * 16 + r];
        d[0] = mx[m][qi]; d[1] = l[m][qi];
        d[2] = acc[m][qi][0]; d[3] = acc[m][qi][1]; d[4] = acc[m][qi][2];
      }
  }
  __syncthreads();

  // final cross-wave merge + output: one thread per q-row
  if (tid < 32) {
    const int q = tid;
    float res[2][3];
    #pragma unroll
    for (int m = 0; m < 2; ++m) {
      float M = -1e30f, L = 0.f, A0 = 0.f, A1 = 0.f, A2 = 0.f;
      #pragma unroll
      for (int ww = 0; ww < 8; ++ww) {
        const float* d = Mg[ww][m][q];
        float mn = fmaxf(M, d[0]);
        float e1 = __expf(M - mn), e2 = __expf(d[0] - mn);
        L = L * e1 + d[1] * e2;
        A0 = A0 * e1 + d[2] * e2;
        A1 = A1 * e1 + d[3] * e2;
        A2 = A2 * e1 + d[4] * e2;
        M = mn;
      }
      float iL = 1.0f / L;
      res[m][0] = A0 * iL; res[m][1] = A1 * iL; res[m][2] = A2 * iL;
    }
    const int maskv = seq_mask[b * SEQ + step];
    const int qg = q0 + q;
    float* ov = out + ((long)(b * STEPS + step) * HW + qg) * CV;
    float* po = pv_out + ((long)(b * HW + qg)) * CV;
    const float* vr = v + ((long)(b * SEQ + step) * HW + qg) * CV;
    #pragma unroll
    for (int c = 0; c < CV; ++c) {
      float rec = 0.9f * res[0][c] + 0.1f * res[1][c];  // COEF_MEMORY = 0.1
      ov[c] = rec;
      po[c] = maskv ? vr[c] : rec;
    }
  }
}

extern "C" void kernel_launch(void* const* d_in, const int* in_sizes, int n_in,
                              void* d_out, int out_size, void* d_ws, size_t ws_size,
                              hipStream_t stream) {
  const float* k   = (const float*)d_in[0];
  const float* v   = (const float*)d_in[1];
  const float* att = (const float*)d_in[2];
  const int* seq_mask = (const int*)d_in[3];
  float* out = (float*)d_out;
  char* ws = (char*)d_ws;

  // workspace layout (~130.4 MB of the 512 MiB ws):
  // kh_all 67,108,864 | m_kh_all 62,914,560 | pvA,pvB,mvA,mvB 4x98,304
  const size_t KH_ALL  = (size_t)BS * SEQ * HW * CK * 2;
  const size_t MKH_ALL = (size_t)BS * STEPS * HW * CK * 2;
  const size_t SV      = (size_t)BS * HW * CV * 4;

  u16*   kh_all   = (u16*)(ws);
  u16*   m_kh_all = (u16*)(ws + KH_ALL);
  float* pvA      = (float*)(ws + KH_ALL + MKH_ALL);
  float* pvB      = (float*)(ws + KH_ALL + MKH_ALL + SV);
  float* mvA      = (float*)(ws + KH_ALL + MKH_ALL + 2 * SV);
  float* mvB      = (float*)(ws + KH_ALL + MKH_ALL + 3 * SV);

  // one parallel kernel: all conversions + m_k scan + pv0/mv0 init + gt copy
  scan_state<<<1024, 256, 0, stream>>>(k, v, att, kh_all, m_kh_all, pvA, mvA, out);

  // serial chain: 15 attention steps only
  for (int i = 0; i < STEPS; ++i) {
    float* pin  = (i & 1) ? pvB : pvA;
    float* pout = (i & 1) ? pvA : pvB;
    float* mvi  = (i & 1) ? mvB : mvA;
    float* mvo  = (i & 1) ? mvA : mvB;
    attn_step<<<dim3(BS, 32), 512, 0, stream>>>(kh_all, m_kh_all, v, seq_mask,
                                                att, mvi, mvo, pin, pout, out, i);
  }
}